// Round 11
// baseline (319.418 us; speedup 1.0000x reference)
//
#include <hip/hip_runtime.h>

typedef unsigned short u16;
typedef unsigned int   u32;
typedef unsigned long long u64;

using bf16x8 = __attribute__((ext_vector_type(8))) __bf16;
using f32x4  = __attribute__((ext_vector_type(4))) float;
using us8    = __attribute__((ext_vector_type(8))) u16;
using us4v   = __attribute__((ext_vector_type(4))) u16;
using u32x4  = __attribute__((ext_vector_type(4))) u32;

#define NB_TOK   4096
#define DD       512
#define HDIM     2048
#define SEQ      2048
#define EPS_F32  1.1920929e-7f
// exp2-domain softmax shift: 16 * log2(e)
#define SM_SHIFT2 23.083120654223414f
// q-projection scale: (1/8) * log2(e), folds the exp->exp2 conversion
#define Q_SCALE   0.18033688011112042f

__device__ __forceinline__ u16 f32_to_bf16(float f) {
  u32 u = __float_as_uint(f);
  u += 0x7fffu + ((u >> 16) & 1u);
  return (u16)(u >> 16);
}
__device__ __forceinline__ float bf16_to_f32(u16 h) {
  return __uint_as_float(((u32)h) << 16);
}
__device__ __forceinline__ bf16x8 ld_frag(const u16* p) {
  return __builtin_bit_cast(bf16x8, *(const us8*)p);
}
__device__ __forceinline__ void gload_lds16(const void* g, void* l) {
  __builtin_amdgcn_global_load_lds(
      (__attribute__((address_space(1))) void*)(void*)g,
      (__attribute__((address_space(3))) void*)l, 16, 0, 0);
}

// ---------------------------------------------------------------------------
// fused preprocessing: weight f32->bf16 | mask pack | rmsnorm1
// ---------------------------------------------------------------------------
__global__ __launch_bounds__(256) void k_pre(
    const float* __restrict__ wq, const float* __restrict__ wk,
    const float* __restrict__ wv, const float* __restrict__ w1,
    const float* __restrict__ w2, const float* __restrict__ w3,
    const int* __restrict__ da, const float* __restrict__ x,
    const float* __restrict__ g1,
    u16* __restrict__ wqkv, u16* __restrict__ w1b,
    u16* __restrict__ w2b, u16* __restrict__ w3b,
    u64* __restrict__ maskT, u16* __restrict__ xn) {
  int bx = blockIdx.x;
  if (bx < 3840) {                     // ---- weight convert ----
    int e = (bx * 256 + threadIdx.x) * 4;
    const float* src; u16* dst; int off;
    if      (e <  262144) { src = wq; dst = wqkv;          off = e; }
    else if (e <  524288) { src = wk; dst = wqkv + 262144; off = e -  262144; }
    else if (e <  786432) { src = wv; dst = wqkv + 524288; off = e -  524288; }
    else if (e < 1835008) { src = w1; dst = w1b;           off = e -  786432; }
    else if (e < 2883584) { src = w2; dst = w2b;           off = e - 1835008; }
    else                  { src = w3; dst = w3b;           off = e - 2883584; }
    float4 v = *(const float4*)(src + off);
    us4v o;
    o[0] = f32_to_bf16(v.x); o[1] = f32_to_bf16(v.y);
    o[2] = f32_to_bf16(v.z); o[3] = f32_to_bf16(v.w);
    *(us4v*)(dst + off) = o;
  } else if (bx < 4864) {              // ---- mask pack ----
    int lane = threadIdx.x & 63, wave = threadIdx.x >> 6;
    int row = (bx - 3840) * 4 + wave;
    int b = row >> 11, r = row & 2047;
    const int* src = da + (size_t)row * SEQ;
    #pragma unroll 4
    for (int w = 0; w < 32; ++w) {
      int d = src[w * 64 + lane];
      u64 bal = __ballot(d != 0);
      if (lane == 0) maskT[((size_t)(b * 32 + w)) * SEQ + r] = bal;
    }
  } else {                             // ---- rmsnorm1 ----
    int lane = threadIdx.x & 63, wave = threadIdx.x >> 6;
    int row = (bx - 4864) * 4 + wave;
    size_t base = (size_t)row * DD + lane * 8;
    float4 a = *(const float4*)(x + base);
    float4 b = *(const float4*)(x + base + 4);
    float ss = a.x*a.x + a.y*a.y + a.z*a.z + a.w*a.w
             + b.x*b.x + b.y*b.y + b.z*b.z + b.w*b.w;
    #pragma unroll
    for (int m = 1; m < 64; m <<= 1) ss += __shfl_xor(ss, m);
    float sc = rsqrtf(ss * (1.0f / DD) + EPS_F32);
    float4 ga = *(const float4*)(g1 + lane * 8);
    float4 gb = *(const float4*)(g1 + lane * 8 + 4);
    us8 o;
    o[0] = f32_to_bf16(a.x * sc * ga.x); o[1] = f32_to_bf16(a.y * sc * ga.y);
    o[2] = f32_to_bf16(a.z * sc * ga.z); o[3] = f32_to_bf16(a.w * sc * ga.w);
    o[4] = f32_to_bf16(b.x * sc * gb.x); o[5] = f32_to_bf16(b.y * sc * gb.y);
    o[6] = f32_to_bf16(b.z * sc * gb.z); o[7] = f32_to_bf16(b.w * sc * gb.w);
    *(us8*)(xn + base) = o;
  }
}

// ---------------------------------------------------------------------------
// GEMM core: 128(M) x 64(N) tile, BK=32, double-buffered LDS, prefetch-then-
// compute, ONE barrier per iter. A and B both K-contiguous (C = A @ B^T).
// ---------------------------------------------------------------------------
template <int NB>
__device__ __forceinline__ void gemm32(const u16* __restrict__ A,
                                       const u16* __restrict__ B0,
                                       const u16* __restrict__ B1,
                                       int K, int mblk, int nblk,
                                       int kbeg, int iters,
                                       u16* lA, u16* lB,
                                       f32x4 (*acc)[4][2]) {
  const int lane = threadIdx.x & 63, wave = threadIdx.x >> 6;
  const int l15 = lane & 15, quad = lane >> 4;
  const int wmt = (wave >> 1) * 4, wnt = (wave & 1) * 2;
  constexpr int CPW = 2 + NB;   // (8 A-chunks + NB*4 B-chunks) / 4 waves

  auto stage = [&](int buf, int k0) {
    #pragma unroll
    for (int i = 0; i < CPW; ++i) {
      int id = wave * CPW + i;
      if (id < 8) {
        gload_lds16(A + (size_t)(mblk + id * 16 + l15) * K + k0 + quad * 8,
                    lA + buf * 4096 + id * 512);
      } else {
        int id2 = id - 8, bi = id2 >> 2, nt = id2 & 3;
        const u16* B = bi ? B1 : B0;
        gload_lds16(B + (size_t)(nblk + nt * 16 + l15) * K + k0 + quad * 8,
                    lB + bi * 4096 + buf * 2048 + nt * 512);
      }
    }
  };

  stage(0, kbeg);
  __syncthreads();
  for (int it = 0; it < iters; ++it) {
    if (it + 1 < iters) stage((it + 1) & 1, kbeg + (it + 1) * 32);
    int buf = it & 1;
    bf16x8 af[4];
    #pragma unroll
    for (int mt = 0; mt < 4; ++mt)
      af[mt] = ld_frag(lA + buf * 4096 + (wmt + mt) * 512 + lane * 8);
    #pragma unroll
    for (int bi = 0; bi < NB; ++bi)
      #pragma unroll
      for (int nt = 0; nt < 2; ++nt) {
        bf16x8 b = ld_frag(lB + bi * 4096 + buf * 2048 + (wnt + nt) * 512 + lane * 8);
        #pragma unroll
        for (int mt = 0; mt < 4; ++mt)
          acc[bi][mt][nt] = __builtin_amdgcn_mfma_f32_16x16x32_bf16(
              af[mt], b, acc[bi][mt][nt], 0, 0, 0);
      }
    __syncthreads();
  }
}

// ---------------------------------------------------------------------------
// QKV projection; grid (32 mblk fast, 8 nblk, 3 z). z=0: q (scaled by
// 0.125*log2e for the exp2 softmax), z=1: k, z=2: v written transposed to
// vT[bh*64+d][tok].
// ---------------------------------------------------------------------------
__global__ __launch_bounds__(256, 4) void k_qkv(const u16* __restrict__ xn,
                                                const u16* __restrict__ wqkv,
                                                const float* __restrict__ bq,
                                                const float* __restrict__ bk,
                                                const float* __restrict__ bv,
                                                u16* __restrict__ qb,
                                                u16* __restrict__ kb,
                                                u16* __restrict__ vt) {
  __shared__ u16 lA[8192], lB[4096];
  int z = blockIdx.z;
  const u16* Bp = wqkv + z * (DD * DD);
  const float* bias = (z == 0) ? bq : ((z == 1) ? bk : bv);
  float scale = (z == 0) ? Q_SCALE : 1.0f;
  int mblk = blockIdx.x * 128, nblk = blockIdx.y * 64;
  f32x4 acc[1][4][2];
  #pragma unroll
  for (int mt = 0; mt < 4; ++mt)
    #pragma unroll
    for (int nt = 0; nt < 2; ++nt) acc[0][mt][nt] = (f32x4)0.0f;
  gemm32<1>(xn, Bp, nullptr, DD, mblk, nblk, 0, 16, lA, lB, acc);
  int lane = threadIdx.x & 63, wave = threadIdx.x >> 6;
  int l15 = lane & 15, quad = lane >> 4;
  int wm = (wave >> 1) * 64, wn = (wave & 1) * 32;
  if (z < 2) {
    u16* out = z ? kb : qb;
    #pragma unroll
    for (int mt = 0; mt < 4; ++mt)
      #pragma unroll
      for (int nt = 0; nt < 2; ++nt) {
        int n = nblk + wn + nt * 16 + l15;
        float bn = bias[n];
        #pragma unroll
        for (int r = 0; r < 4; ++r) {
          int m = mblk + wm + mt * 16 + quad * 4 + r;
          out[(size_t)m * DD + n] = f32_to_bf16((acc[0][mt][nt][r] + bn) * scale);
        }
      }
  } else {
    #pragma unroll
    for (int mt = 0; mt < 4; ++mt)
      #pragma unroll
      for (int nt = 0; nt < 2; ++nt) {
        int n = nblk + wn + nt * 16 + l15;
        float bn = bias[n];
        int m = mblk + wm + mt * 16 + quad * 4;
        int b = m >> 11, tok = m & 2047;
        us4v o;
        #pragma unroll
        for (int r = 0; r < 4; ++r) o[r] = f32_to_bf16(acc[0][mt][nt][r] + bn);
        *(us4v*)(vt + ((size_t)(b * 8 + (n >> 6)) * 64 + (n & 63)) * SEQ + tok) = o;
      }
  }
}

// ---------------------------------------------------------------------------
// Flash attention, ZERO-LDS / ZERO-BARRIER: 128 q-rows/block, kv-quarter z
// (512 kv, 8 tiles of 64). K and V fragments are loaded DIRECTLY from global
// to registers (both are 16B/lane contiguous: K A-frag row=kv,k=d from kb;
// V B-frag row=d,k=kv from vT). 4x per-wave redundancy is served by L2.
// Waves are fully independent — no __syncthreads anywhere.
// S^T = K·Q^T; exp2 softmax; P transposed in-register via ds_bpermute
// (crossbar, no LDS storage); l via ones-column MFMA.
// Partials (O bf16, l f32) merged in k_rms2. grid (16 q, 16 bh, 4 z).
// ---------------------------------------------------------------------------
__global__ __launch_bounds__(256, 4) void k_attn(const u16* __restrict__ q,
                                                 const u16* __restrict__ k,
                                                 const u16* __restrict__ vT,
                                                 const u64* __restrict__ maskT,
                                                 u16* __restrict__ Opart,
                                                 float* __restrict__ lpart) {
  int tid = threadIdx.x, lane = tid & 63, wave = tid >> 6;
  int l15 = lane & 15, quad = lane >> 4;
  int bh = blockIdx.y, b = bh >> 3, h = bh & 7;
  int q0 = blockIdx.x * 128;
  int z = blockIdx.z;
  int kvbase = z * 512;
  // K A-frag base: row kv = l15 (+tile), k = d = ks*32 + quad*8
  const u16* kg = k + (size_t)(b * SEQ + kvbase + l15) * DD + h * 64 + quad * 8;
  // V B-frag base: row d = l15 (+dt*16), k = kv = ks*32 + quad*8
  const u16* vg = vT + (size_t)(bh * 64 + l15) * SEQ + kvbase + quad * 8;
  const u64* mg = maskT + ((size_t)(b * 32 + z * 8)) * SEQ + q0 + wave * 32 + l15;

  // Q fragments direct global->register (B-operand layout: row = q-col)
  const u16* qrow = q + (size_t)(b * SEQ + q0 + wave * 32 + l15) * DD + h * 64;
  bf16x8 qa[2][2];
  #pragma unroll
  for (int nq = 0; nq < 2; ++nq)
    #pragma unroll
    for (int ks = 0; ks < 2; ++ks)
      qa[nq][ks] = ld_frag(qrow + (size_t)nq * 16 * DD + ks * 32 + quad * 8);

  // ones B-fragment for the l-column MFMA (bf16 1.0 = 0x3f80)
  us8 ones_u;
  #pragma unroll
  for (int j = 0; j < 8; ++j) ones_u[j] = 0x3f80;
  const bf16x8 ones = __builtin_bit_cast(bf16x8, ones_u);

  // bpermute indices (bytes): srcA = l15 + 32*(Q&1); srcB = srcA + 16
  const int idxA = (l15 + ((lane & 16) << 1)) * 4;
  const int idxB = idxA + 64;
  const bool hiTile = (quad & 2) != 0;

  f32x4 oa[2][4], oal[2];
  #pragma unroll
  for (int mq = 0; mq < 2; ++mq) {
    oal[mq] = (f32x4)0.0f;
    #pragma unroll
    for (int dt = 0; dt < 4; ++dt) oa[mq][dt] = (f32x4)0.0f;
  }

  u64 mw[2] = { mg[0], mg[16] };

  for (int t = 0; t < 8; ++t) {
    int kv0 = t * 64;

    // prefetch next tile's mask words (L2-hot)
    u64 mwn[2] = {0, 0};
    if (t + 1 < 8) {
      mwn[0] = mg[(size_t)(t + 1) * SEQ];
      mwn[1] = mg[(size_t)(t + 1) * SEQ + 16];
    }

    // S^T = K·Q^T: rows kv (4 mt tiles), cols q (2 nq per wave).
    // K fragments straight from global (16B/lane, L2-served).
    f32x4 sa[2][4];
    #pragma unroll
    for (int nq = 0; nq < 2; ++nq)
      #pragma unroll
      for (int mt = 0; mt < 4; ++mt) sa[nq][mt] = (f32x4)0.0f;
    #pragma unroll
    for (int ks = 0; ks < 2; ++ks) {
      bf16x8 ka[4];
      #pragma unroll
      for (int mt = 0; mt < 4; ++mt)
        ka[mt] = ld_frag(kg + (size_t)(kv0 + mt * 16) * DD + ks * 32);
      #pragma unroll
      for (int nq = 0; nq < 2; ++nq)
        #pragma unroll
        for (int mt = 0; mt < 4; ++mt)
          sa[nq][mt] = __builtin_amdgcn_mfma_f32_16x16x32_bf16(
              ka[mt], qa[nq][ks], sa[nq][mt], 0, 0, 0);
    }

    // p = mask ? exp2(s' - SHIFT2) : 0, truncate-pack to bf16 pairs in regs
    u32 pk[2][4][2];   // [nq][mt][lo/hi]
    #pragma unroll
    for (int nq = 0; nq < 2; ++nq) {
      u64 mq64 = mw[nq] >> (quad * 4);
      #pragma unroll
      for (int mt = 0; mt < 4; ++mt) {
        u32 nib = (u32)(mq64 >> (mt * 16)) & 0xFu;
        u32 pb[4];
        #pragma unroll
        for (int r = 0; r < 4; ++r) {
          float p = __builtin_amdgcn_exp2f(sa[nq][mt][r] - SM_SHIFT2);
          p = (nib >> r) & 1u ? p : 0.0f;
          pb[r] = __float_as_uint(p);
        }
        pk[nq][mt][0] = __builtin_amdgcn_perm(pb[1], pb[0], 0x07060302u);
        pk[nq][mt][1] = __builtin_amdgcn_perm(pb[3], pb[2], 0x07060302u);
      }
    }

    // O += P @ V ; l += P @ ones. P A-frags via ds_bpermute (crossbar only).
    // V fragments straight from global (16B/lane, L2-served).
    #pragma unroll
    for (int ks = 0; ks < 2; ++ks) {
      bf16x8 vb[4];
      #pragma unroll
      for (int dt = 0; dt < 4; ++dt)
        vb[dt] = ld_frag(vg + (size_t)(dt * 16) * SEQ + kv0 + ks * 32);
      #pragma unroll
      for (int mq = 0; mq < 2; ++mq) {
        u32x4 regv;
        #pragma unroll
        for (int jr = 0; jr < 4; ++jr) {
          int idx = (jr < 2) ? idxA : idxB;
          int sel = jr & 1;
          u32 va = (u32)__builtin_amdgcn_ds_bpermute(idx, (int)pk[mq][2 * ks][sel]);
          u32 vbv = (u32)__builtin_amdgcn_ds_bpermute(idx, (int)pk[mq][2 * ks + 1][sel]);
          regv[jr] = hiTile ? vbv : va;
        }
        bf16x8 pa = __builtin_bit_cast(bf16x8, regv);
        #pragma unroll
        for (int dt = 0; dt < 4; ++dt)
          oa[mq][dt] = __builtin_amdgcn_mfma_f32_16x16x32_bf16(
              pa, vb[dt], oa[mq][dt], 0, 0, 0);
        oal[mq] = __builtin_amdgcn_mfma_f32_16x16x32_bf16(
            pa, ones, oal[mq], 0, 0, 0);
      }
    }

    mw[0] = mwn[0]; mw[1] = mwn[1];
  }

  // l: every lane's oal[mq][r] = full row-sum for row mq*16+quad*4+r
  if (l15 == 0) {
    #pragma unroll
    for (int mq = 0; mq < 2; ++mq)
      #pragma unroll
      for (int r = 0; r < 4; ++r)
        lpart[((size_t)z * 16 + bh) * SEQ + q0 + wave * 32 + mq * 16 + quad * 4 + r] =
            oal[mq][r];
  }

  u16* Og = Opart + (size_t)z * NB_TOK * DD;
  #pragma unroll
  for (int mq = 0; mq < 2; ++mq)
    #pragma unroll
    for (int r = 0; r < 4; ++r) {
      int m = q0 + wave * 32 + mq * 16 + quad * 4 + r;
      u16* dst = Og + (size_t)(b * SEQ + m) * DD + h * 64;
      #pragma unroll
      for (int dt = 0; dt < 4; ++dt)
        dst[dt * 16 + l15] = f32_to_bf16(oa[mq][dt][r]);
    }
}

// ---------------------------------------------------------------------------
// merge 4 O/l partials + residual + rmsnorm2 + out-init (h + b3)
// ---------------------------------------------------------------------------
__global__ __launch_bounds__(256) void k_rms2(const float* __restrict__ x,
                                              const u16* __restrict__ Opart,
                                              const float* __restrict__ lpart,
                                              const float* __restrict__ b3,
                                              const float* __restrict__ g2,
                                              float* __restrict__ outinit,
                                              u16* __restrict__ hn) {
  int lane = threadIdx.x & 63, wave = threadIdx.x >> 6;
  int row = blockIdx.x * 4 + wave;
  int b = row >> 11, tok = row & 2047, hh = lane >> 3;
  size_t base = (size_t)row * DD + lane * 8;
  float lsum = 0.0f;
  #pragma unroll
  for (int z = 0; z < 4; ++z)
    lsum += lpart[((size_t)(z * 16 + b * 8 + hh)) * SEQ + tok];
  float inv = (lsum > 0.0f) ? (1.0f / lsum) : 0.0f;
  float ov[8] = {0,0,0,0,0,0,0,0};
  #pragma unroll
  for (int z = 0; z < 4; ++z) {
    us8 o = *(const us8*)(Opart + (size_t)z * NB_TOK * DD + base);
    #pragma unroll
    for (int j = 0; j < 8; ++j) ov[j] += bf16_to_f32(o[j]);
  }
  float4 a = *(const float4*)(x + base);
  float4 bb = *(const float4*)(x + base + 4);
  float hv[8];
  hv[0] = a.x  + ov[0] * inv; hv[1] = a.y  + ov[1] * inv;
  hv[2] = a.z  + ov[2] * inv; hv[3] = a.w  + ov[3] * inv;
  hv[4] = bb.x + ov[4] * inv; hv[5] = bb.y + ov[5] * inv;
  hv[6] = bb.z + ov[6] * inv; hv[7] = bb.w + ov[7] * inv;
  float ss = 0.0f;
  #pragma unroll
  for (int j = 0; j < 8; ++j) ss += hv[j] * hv[j];
  #pragma unroll
  for (int m = 1; m < 64; m <<= 1) ss += __shfl_xor(ss, m);
  float sc = rsqrtf(ss * (1.0f / DD) + EPS_F32);
  float4 c0 = *(const float4*)(b3 + lane * 8);
  float4 c1 = *(const float4*)(b3 + lane * 8 + 4);
  float4 w0 = {hv[0] + c0.x, hv[1] + c0.y, hv[2] + c0.z, hv[3] + c0.w};
  float4 w1 = {hv[4] + c1.x, hv[5] + c1.y, hv[6] + c1.z, hv[7] + c1.w};
  *(float4*)(outinit + base) = w0;
  *(float4*)(outinit + base + 4) = w1;
  float4 ga = *(const float4*)(g2 + lane * 8);
  float4 gb = *(const float4*)(g2 + lane * 8 + 4);
  us8 hb;
  hb[0] = f32_to_bf16(hv[0] * sc * ga.x); hb[1] = f32_to_bf16(hv[1] * sc * ga.y);
  hb[2] = f32_to_bf16(hv[2] * sc * ga.z); hb[3] = f32_to_bf16(hv[3] * sc * ga.w);
  hb[4] = f32_to_bf16(hv[4] * sc * gb.x); hb[5] = f32_to_bf16(hv[5] * sc * gb.y);
  hb[6] = f32_to_bf16(hv[6] * sc * gb.z); hb[7] = f32_to_bf16(hv[7] * sc * gb.w);
  *(us8*)(hn + base) = hb;
}

// ---------------------------------------------------------------------------
// FFN1+FFN2 fused; grid (32 mblk fast, 32 nblk of 64)
// ---------------------------------------------------------------------------
__global__ __launch_bounds__(256, 4) void k_ffn12(const u16* __restrict__ hn,
                                                  const u16* __restrict__ w1,
                                                  const u16* __restrict__ w2,
                                                  const float* __restrict__ b1,
                                                  const float* __restrict__ b2,
                                                  u16* __restrict__ g) {
  __shared__ u16 lA[8192], lB[8192];
  int mblk = blockIdx.x * 128, nblk = blockIdx.y * 64;
  f32x4 acc[2][4][2];
  #pragma unroll
  for (int bi = 0; bi < 2; ++bi)
    #pragma unroll
    for (int mt = 0; mt < 4; ++mt)
      #pragma unroll
      for (int nt = 0; nt < 2; ++nt) acc[bi][mt][nt] = (f32x4)0.0f;
  gemm32<2>(hn, w1, w2, DD, mblk, nblk, 0, 16, lA, lB, acc);
  int lane = threadIdx.x & 63, wave = threadIdx.x >> 6;
  int l15 = lane & 15, quad = lane >> 4;
  int wm = (wave >> 1) * 64, wn = (wave & 1) * 32;
  #pragma unroll
  for (int mt = 0; mt < 4; ++mt)
    #pragma unroll
    for (int nt = 0; nt < 2; ++nt) {
      int n = nblk + wn + nt * 16 + l15;
      float bb1 = b1[n], bb2 = b2[n];
      #pragma unroll
      for (int r = 0; r < 4; ++r) {
        int m = mblk + wm + mt * 16 + quad * 4 + r;
        float x2 = acc[0][mt][nt][r] + bb1;
        float x3 = acc[1][mt][nt][r] + bb2;
        float si = x2 / (1.0f + __expf(-x2));
        g[(size_t)m * HDIM + n] = f32_to_bf16(si * x3);
      }
    }
}

// ---------------------------------------------------------------------------
// FFN3 split-K=2, NO atomics: partial[z] = g[:, z*1024:(z+1)*1024] @ W3^T
// slice. grid (32 mblk fast, 8 nblk of 64, 2 z). f32 partials to workspace.
// ---------------------------------------------------------------------------
__global__ __launch_bounds__(256, 4) void k_ffn3(const u16* __restrict__ g,
                                                 const u16* __restrict__ w3,
                                                 float* __restrict__ p0,
                                                 float* __restrict__ p1) {
  __shared__ u16 lA[8192], lB[4096];
  int mblk = blockIdx.x * 128, nblk = blockIdx.y * 64, z = blockIdx.z;
  f32x4 acc[1][4][2];
  #pragma unroll
  for (int mt = 0; mt < 4; ++mt)
    #pragma unroll
    for (int nt = 0; nt < 2; ++nt) acc[0][mt][nt] = (f32x4)0.0f;
  gemm32<1>(g, w3, nullptr, HDIM, mblk, nblk, z * 1024, 32, lA, lB, acc);
  float* dst = z ? p1 : p0;
  int lane = threadIdx.x & 63, wave = threadIdx.x >> 6;
  int l15 = lane & 15, quad = lane >> 4;
  int wm = (wave >> 1) * 64, wn = (wave & 1) * 32;
  #pragma unroll
  for (int mt = 0; mt < 4; ++mt)
    #pragma unroll
    for (int nt = 0; nt < 2; ++nt) {
      int n = nblk + wn + nt * 16 + l15;
      #pragma unroll
      for (int r = 0; r < 4; ++r) {
        int m = mblk + wm + mt * 16 + quad * 4 + r;
        dst[(size_t)m * DD + n] = acc[0][mt][nt][r];
      }
    }
}

// ---------------------------------------------------------------------------
// merge: out(pre-inited h+b3) += p0 + p1.  2M f32 elems, float4 streaming.
// ---------------------------------------------------------------------------
__global__ __launch_bounds__(256) void k_fmerge(const float* __restrict__ p0,
                                                const float* __restrict__ p1,
                                                float* __restrict__ out) {
  int e = (blockIdx.x * 256 + threadIdx.x) * 4;
  float4 a = *(const float4*)(p0 + e);
  float4 b = *(const float4*)(p1 + e);
  float4 o = *(const float4*)(out + e);
  o.x += a.x + b.x; o.y += a.y + b.y;
  o.z += a.z + b.z; o.w += a.w + b.w;
  *(float4*)(out + e) = o;
}

// ---------------------------------------------------------------------------
// workspace layout (bytes).  p0/p1 reuse regions dead after qkv/attn:
// p0 = MB16 (qb+kb region, 8 MB), p1 = MB0 (xn+wqkv region, 8 MB).
// ---------------------------------------------------------------------------
#define MB(x) ((size_t)(x) * 1048576)
#define WS_XN    MB(0)     // 4 MiB  bf16 [4096][512]   (dead after k_qkv)
#define WS_WQKV  MB(4)     // 1.5                       (dead after k_qkv)
#define WS_W1B   MB(6)     // 2
#define WS_W2B   MB(8)     // 2
#define WS_W3B   MB(10)    // 2
#define WS_MASK  MB(12)    // 1   u64 [2][32][2048]
#define WS_QB    MB(16)    // 4                          (dead after k_attn)
#define WS_KB    MB(20)    // 4                          (dead after k_attn)
#define WS_VT    MB(24)    // 4   bf16 [16*64][2048]     (dead after k_attn)
#define WS_OP    MB(28)    // 16  bf16 [4][4096][512]
#define WS_LP    MB(44)    // 0.5 f32 [4][16][2048]
#define WS_HN    MB(45)    // 4
#define WS_G     MB(49)    // 16
#define WS_P0    MB(16)    // 8   f32 [4096][512] ffn3 partial z=0
#define WS_P1    MB(0)     // 8   f32 [4096][512] ffn3 partial z=1

extern "C" void kernel_launch(void* const* d_in, const int* in_sizes, int n_in,
                              void* d_out, int out_size, void* d_ws, size_t ws_size,
                              hipStream_t stream) {
  (void)in_sizes; (void)n_in; (void)out_size; (void)ws_size;
  const float* x  = (const float*)d_in[0];
  const int*   DA = (const int*)d_in[1];
  const float* Wq = (const float*)d_in[2];
  const float* bq = (const float*)d_in[3];
  const float* Wk = (const float*)d_in[4];
  const float* bk = (const float*)d_in[5];
  const float* Wv = (const float*)d_in[6];
  const float* bv = (const float*)d_in[7];
  const float* W1 = (const float*)d_in[8];
  const float* b1 = (const float*)d_in[9];
  const float* W2 = (const float*)d_in[10];
  const float* b2 = (const float*)d_in[11];
  const float* W3 = (const float*)d_in[12];
  const float* b3 = (const float*)d_in[13];
  const float* g1 = (const float*)d_in[14];
  const float* g2 = (const float*)d_in[15];
  float* out = (float*)d_out;
  char* w = (char*)d_ws;

  u16* xn   = (u16*)(w + WS_XN);
  u16* wqkv = (u16*)(w + WS_WQKV);
  u16* w1b  = (u16*)(w + WS_W1B);
  u16* w2b  = (u16*)(w + WS_W2B);
  u16* w3b  = (u16*)(w + WS_W3B);
  u64* mskT = (u64*)(w + WS_MASK);
  u16* qb   = (u16*)(w + WS_QB);
  u16* kb   = (u16*)(w + WS_KB);
  u16* vt   = (u16*)(w + WS_VT);
  u16* Op   = (u16*)(w + WS_OP);
  float* lp = (float*)(w + WS_LP);
  u16* hn   = (u16*)(w + WS_HN);
  u16* gb   = (u16*)(w + WS_G);
  float* p0 = (float*)(w + WS_P0);
  float* p1 = (float*)(w + WS_P1);

  k_pre<<<5888, 256, 0, stream>>>(Wq, Wk, Wv, W1, W2, W3, DA, x, g1,
                                  wqkv, w1b, w2b, w3b, mskT, xn);
  k_qkv<<<dim3(32, 8, 3), 256, 0, stream>>>(xn, wqkv, bq, bk, bv, qb, kb, vt);
  k_attn<<<dim3(16, 16, 4), 256, 0, stream>>>(qb, kb, vt, mskT, Op, lp);
  k_rms2<<<1024, 256, 0, stream>>>(x, Op, lp, b3, g2, out, hn);
  k_ffn12<<<dim3(32, 32), 256, 0, stream>>>(hn, w1b, w2b, b1, b2, gb);
  k_ffn3<<<dim3(32, 8, 2), 256, 0, stream>>>(gb, w3b, p0, p1);
  k_fmerge<<<2048, 256, 0, stream>>>(p0, p1, out);
}

// Round 12
// 267.543 us; speedup vs baseline: 1.1939x; 1.1939x over previous
//
#include <hip/hip_runtime.h>

typedef unsigned short u16;
typedef unsigned int   u32;
typedef unsigned long long u64;

using bf16x8 = __attribute__((ext_vector_type(8))) __bf16;
using f32x4  = __attribute__((ext_vector_type(4))) float;
using us8    = __attribute__((ext_vector_type(8))) u16;
using us4v   = __attribute__((ext_vector_type(4))) u16;
using u32x4  = __attribute__((ext_vector_type(4))) u32;

#define NB_TOK   4096
#define DD       512
#define HDIM     2048
#define SEQ      2048
#define EPS_F32  1.1920929e-7f
// exp2-domain softmax shift: 16 * log2(e)
#define SM_SHIFT2 23.083120654223414f
// q-projection scale: (1/8) * log2(e), folds the exp->exp2 conversion
#define Q_SCALE   0.18033688011112042f

__device__ __forceinline__ u16 f32_to_bf16(float f) {
  u32 u = __float_as_uint(f);
  u += 0x7fffu + ((u >> 16) & 1u);
  return (u16)(u >> 16);
}
__device__ __forceinline__ float bf16_to_f32(u16 h) {
  return __uint_as_float(((u32)h) << 16);
}
__device__ __forceinline__ bf16x8 ld_frag(const u16* p) {
  return __builtin_bit_cast(bf16x8, *(const us8*)p);
}
__device__ __forceinline__ void gload_lds16(const void* g, void* l) {
  __builtin_amdgcn_global_load_lds(
      (__attribute__((address_space(1))) void*)(void*)g,
      (__attribute__((address_space(3))) void*)l, 16, 0, 0);
}

// ---------------------------------------------------------------------------
// fused preprocessing: weight f32->bf16 | mask pack | rmsnorm1
// ---------------------------------------------------------------------------
__global__ __launch_bounds__(256) void k_pre(
    const float* __restrict__ wq, const float* __restrict__ wk,
    const float* __restrict__ wv, const float* __restrict__ w1,
    const float* __restrict__ w2, const float* __restrict__ w3,
    const int* __restrict__ da, const float* __restrict__ x,
    const float* __restrict__ g1,
    u16* __restrict__ wqkv, u16* __restrict__ w1b,
    u16* __restrict__ w2b, u16* __restrict__ w3b,
    u64* __restrict__ maskT, u16* __restrict__ xn) {
  int bx = blockIdx.x;
  if (bx < 3840) {                     // ---- weight convert ----
    int e = (bx * 256 + threadIdx.x) * 4;
    const float* src; u16* dst; int off;
    if      (e <  262144) { src = wq; dst = wqkv;          off = e; }
    else if (e <  524288) { src = wk; dst = wqkv + 262144; off = e -  262144; }
    else if (e <  786432) { src = wv; dst = wqkv + 524288; off = e -  524288; }
    else if (e < 1835008) { src = w1; dst = w1b;           off = e -  786432; }
    else if (e < 2883584) { src = w2; dst = w2b;           off = e - 1835008; }
    else                  { src = w3; dst = w3b;           off = e - 2883584; }
    float4 v = *(const float4*)(src + off);
    us4v o;
    o[0] = f32_to_bf16(v.x); o[1] = f32_to_bf16(v.y);
    o[2] = f32_to_bf16(v.z); o[3] = f32_to_bf16(v.w);
    *(us4v*)(dst + off) = o;
  } else if (bx < 4864) {              // ---- mask pack ----
    int lane = threadIdx.x & 63, wave = threadIdx.x >> 6;
    int row = (bx - 3840) * 4 + wave;
    int b = row >> 11, r = row & 2047;
    const int* src = da + (size_t)row * SEQ;
    #pragma unroll 4
    for (int w = 0; w < 32; ++w) {
      int d = src[w * 64 + lane];
      u64 bal = __ballot(d != 0);
      if (lane == 0) maskT[((size_t)(b * 32 + w)) * SEQ + r] = bal;
    }
  } else {                             // ---- rmsnorm1 ----
    int lane = threadIdx.x & 63, wave = threadIdx.x >> 6;
    int row = (bx - 4864) * 4 + wave;
    size_t base = (size_t)row * DD + lane * 8;
    float4 a = *(const float4*)(x + base);
    float4 b = *(const float4*)(x + base + 4);
    float ss = a.x*a.x + a.y*a.y + a.z*a.z + a.w*a.w
             + b.x*b.x + b.y*b.y + b.z*b.z + b.w*b.w;
    #pragma unroll
    for (int m = 1; m < 64; m <<= 1) ss += __shfl_xor(ss, m);
    float sc = rsqrtf(ss * (1.0f / DD) + EPS_F32);
    float4 ga = *(const float4*)(g1 + lane * 8);
    float4 gb = *(const float4*)(g1 + lane * 8 + 4);
    us8 o;
    o[0] = f32_to_bf16(a.x * sc * ga.x); o[1] = f32_to_bf16(a.y * sc * ga.y);
    o[2] = f32_to_bf16(a.z * sc * ga.z); o[3] = f32_to_bf16(a.w * sc * ga.w);
    o[4] = f32_to_bf16(b.x * sc * gb.x); o[5] = f32_to_bf16(b.y * sc * gb.y);
    o[6] = f32_to_bf16(b.z * sc * gb.z); o[7] = f32_to_bf16(b.w * sc * gb.w);
    *(us8*)(xn + base) = o;
  }
}

// ---------------------------------------------------------------------------
// GEMM core: 128(M) x 64(N) tile, BK=32, double-buffered LDS, prefetch-then-
// compute, ONE barrier per iter. A and B both K-contiguous (C = A @ B^T).
// ---------------------------------------------------------------------------
template <int NB>
__device__ __forceinline__ void gemm32(const u16* __restrict__ A,
                                       const u16* __restrict__ B0,
                                       const u16* __restrict__ B1,
                                       int K, int mblk, int nblk,
                                       int kbeg, int iters,
                                       u16* lA, u16* lB,
                                       f32x4 (*acc)[4][2]) {
  const int lane = threadIdx.x & 63, wave = threadIdx.x >> 6;
  const int l15 = lane & 15, quad = lane >> 4;
  const int wmt = (wave >> 1) * 4, wnt = (wave & 1) * 2;
  constexpr int CPW = 2 + NB;   // (8 A-chunks + NB*4 B-chunks) / 4 waves

  auto stage = [&](int buf, int k0) {
    #pragma unroll
    for (int i = 0; i < CPW; ++i) {
      int id = wave * CPW + i;
      if (id < 8) {
        gload_lds16(A + (size_t)(mblk + id * 16 + l15) * K + k0 + quad * 8,
                    lA + buf * 4096 + id * 512);
      } else {
        int id2 = id - 8, bi = id2 >> 2, nt = id2 & 3;
        const u16* B = bi ? B1 : B0;
        gload_lds16(B + (size_t)(nblk + nt * 16 + l15) * K + k0 + quad * 8,
                    lB + bi * 4096 + buf * 2048 + nt * 512);
      }
    }
  };

  stage(0, kbeg);
  __syncthreads();
  for (int it = 0; it < iters; ++it) {
    if (it + 1 < iters) stage((it + 1) & 1, kbeg + (it + 1) * 32);
    int buf = it & 1;
    bf16x8 af[4];
    #pragma unroll
    for (int mt = 0; mt < 4; ++mt)
      af[mt] = ld_frag(lA + buf * 4096 + (wmt + mt) * 512 + lane * 8);
    #pragma unroll
    for (int bi = 0; bi < NB; ++bi)
      #pragma unroll
      for (int nt = 0; nt < 2; ++nt) {
        bf16x8 b = ld_frag(lB + bi * 4096 + buf * 2048 + (wnt + nt) * 512 + lane * 8);
        #pragma unroll
        for (int mt = 0; mt < 4; ++mt)
          acc[bi][mt][nt] = __builtin_amdgcn_mfma_f32_16x16x32_bf16(
              af[mt], b, acc[bi][mt][nt], 0, 0, 0);
      }
    __syncthreads();
  }
}

// ---------------------------------------------------------------------------
// QKV projection; grid (32 mblk fast, 8 nblk, 3 z). z=0: q (scaled by
// 0.125*log2e for the exp2 softmax), z=1: k, z=2: v written transposed to
// vT[bh*64+d][tok].
// ---------------------------------------------------------------------------
__global__ __launch_bounds__(256, 4) void k_qkv(const u16* __restrict__ xn,
                                                const u16* __restrict__ wqkv,
                                                const float* __restrict__ bq,
                                                const float* __restrict__ bk,
                                                const float* __restrict__ bv,
                                                u16* __restrict__ qb,
                                                u16* __restrict__ kb,
                                                u16* __restrict__ vt) {
  __shared__ u16 lA[8192], lB[4096];
  int z = blockIdx.z;
  const u16* Bp = wqkv + z * (DD * DD);
  const float* bias = (z == 0) ? bq : ((z == 1) ? bk : bv);
  float scale = (z == 0) ? Q_SCALE : 1.0f;
  int mblk = blockIdx.x * 128, nblk = blockIdx.y * 64;
  f32x4 acc[1][4][2];
  #pragma unroll
  for (int mt = 0; mt < 4; ++mt)
    #pragma unroll
    for (int nt = 0; nt < 2; ++nt) acc[0][mt][nt] = (f32x4)0.0f;
  gemm32<1>(xn, Bp, nullptr, DD, mblk, nblk, 0, 16, lA, lB, acc);
  int lane = threadIdx.x & 63, wave = threadIdx.x >> 6;
  int l15 = lane & 15, quad = lane >> 4;
  int wm = (wave >> 1) * 64, wn = (wave & 1) * 32;
  if (z < 2) {
    u16* out = z ? kb : qb;
    #pragma unroll
    for (int mt = 0; mt < 4; ++mt)
      #pragma unroll
      for (int nt = 0; nt < 2; ++nt) {
        int n = nblk + wn + nt * 16 + l15;
        float bn = bias[n];
        #pragma unroll
        for (int r = 0; r < 4; ++r) {
          int m = mblk + wm + mt * 16 + quad * 4 + r;
          out[(size_t)m * DD + n] = f32_to_bf16((acc[0][mt][nt][r] + bn) * scale);
        }
      }
  } else {
    #pragma unroll
    for (int mt = 0; mt < 4; ++mt)
      #pragma unroll
      for (int nt = 0; nt < 2; ++nt) {
        int n = nblk + wn + nt * 16 + l15;
        float bn = bias[n];
        int m = mblk + wm + mt * 16 + quad * 4;
        int b = m >> 11, tok = m & 2047;
        us4v o;
        #pragma unroll
        for (int r = 0; r < 4; ++r) o[r] = f32_to_bf16(acc[0][mt][nt][r] + bn);
        *(us4v*)(vt + ((size_t)(b * 8 + (n >> 6)) * 64 + (n & 63)) * SEQ + tok) = o;
      }
  }
}

// ---------------------------------------------------------------------------
// Flash attention (round-10 best): 128 q-rows/block, kv-quarter z (512 kv,
// 8 tiles of 64). Q frags direct global->registers. S^T = K·Q^T; exp2
// softmax. P transposed to PV A-layout IN REGISTERS via ds_bpermute (no lP
// round-trip -> 32 KB LDS). l via ones-column MFMA. Mask prefetched.
// One barrier per tile. grid (16 q, 16 bh, 4 z).
// ---------------------------------------------------------------------------
__global__ __launch_bounds__(256, 4) void k_attn(const u16* __restrict__ q,
                                                 const u16* __restrict__ k,
                                                 const u16* __restrict__ vT,
                                                 const u64* __restrict__ maskT,
                                                 u16* __restrict__ Opart,
                                                 float* __restrict__ lpart) {
  __shared__ u16 lK[8192], lV[8192];
  int tid = threadIdx.x, lane = tid & 63, wave = tid >> 6;
  int l15 = lane & 15, quad = lane >> 4;
  int bh = blockIdx.y, b = bh >> 3, h = bh & 7;
  int q0 = blockIdx.x * 128;
  int z = blockIdx.z;
  int kvbase = z * 512;
  const u16* kg = k + (size_t)(b * SEQ + kvbase) * DD + h * 64;
  const u16* vg = vT + (size_t)bh * 64 * SEQ + kvbase;
  const u64* mg = maskT + ((size_t)(b * 32 + z * 8)) * SEQ + q0 + wave * 32 + l15;

  // stage K/V tile 0
  #pragma unroll
  for (int i = 0; i < 2; ++i) {
    int c = wave * 2 + i;
    int mt = c >> 1, ks = c & 1;
    gload_lds16(kg + (size_t)(mt * 16 + l15) * DD + ks * 32 + quad * 8, lK + c * 512);
    gload_lds16(vg + (size_t)(mt * 16 + l15) * SEQ + ks * 32 + quad * 8, lV + c * 512);
  }

  // Q fragments direct global->register (B-operand layout: row = q-col)
  const u16* qrow = q + (size_t)(b * SEQ + q0 + wave * 32 + l15) * DD + h * 64;
  bf16x8 qa[2][2];
  #pragma unroll
  for (int nq = 0; nq < 2; ++nq)
    #pragma unroll
    for (int ks = 0; ks < 2; ++ks)
      qa[nq][ks] = ld_frag(qrow + (size_t)nq * 16 * DD + ks * 32 + quad * 8);
  __syncthreads();

  // ones B-fragment for the l-column MFMA (bf16 1.0 = 0x3f80)
  us8 ones_u;
  #pragma unroll
  for (int j = 0; j < 8; ++j) ones_u[j] = 0x3f80;
  const bf16x8 ones = __builtin_bit_cast(bf16x8, ones_u);

  // bpermute indices (bytes): srcA = l15 + 32*(Q&1); srcB = srcA + 16
  const int idxA = (l15 + ((lane & 16) << 1)) * 4;
  const int idxB = idxA + 64;
  const bool hiTile = (quad & 2) != 0;

  f32x4 oa[2][4], oal[2];
  #pragma unroll
  for (int mq = 0; mq < 2; ++mq) {
    oal[mq] = (f32x4)0.0f;
    #pragma unroll
    for (int dt = 0; dt < 4; ++dt) oa[mq][dt] = (f32x4)0.0f;
  }

  u64 mw[2] = { mg[0], mg[16] };

  for (int t = 0; t < 8; ++t) {
    const u16* lKc = lK + (t & 1) * 4096;
    const u16* lVc = lV + (t & 1) * 4096;

    u64 mwn[2] = {0, 0};
    if (t + 1 < 8) {
      mwn[0] = mg[(size_t)(t + 1) * SEQ];
      mwn[1] = mg[(size_t)(t + 1) * SEQ + 16];
      int kv1 = (t + 1) * 64;
      u16* dK = lK + ((t + 1) & 1) * 4096;
      u16* dV = lV + ((t + 1) & 1) * 4096;
      #pragma unroll
      for (int i = 0; i < 2; ++i) {
        int c = wave * 2 + i;
        int mt = c >> 1, ks = c & 1;
        gload_lds16(kg + (size_t)(kv1 + mt * 16 + l15) * DD + ks * 32 + quad * 8, dK + c * 512);
        gload_lds16(vg + (size_t)(mt * 16 + l15) * SEQ + kv1 + ks * 32 + quad * 8, dV + c * 512);
      }
    }

    // S^T = K·Q^T: rows kv (4 mt tiles), cols q (2 nq per wave)
    f32x4 sa[2][4];
    #pragma unroll
    for (int nq = 0; nq < 2; ++nq)
      #pragma unroll
      for (int mt = 0; mt < 4; ++mt) sa[nq][mt] = (f32x4)0.0f;
    #pragma unroll
    for (int ks = 0; ks < 2; ++ks) {
      bf16x8 ka[4];
      #pragma unroll
      for (int mt = 0; mt < 4; ++mt)
        ka[mt] = ld_frag(lKc + mt * 1024 + ks * 512 + lane * 8);
      #pragma unroll
      for (int nq = 0; nq < 2; ++nq)
        #pragma unroll
        for (int mt = 0; mt < 4; ++mt)
          sa[nq][mt] = __builtin_amdgcn_mfma_f32_16x16x32_bf16(
              ka[mt], qa[nq][ks], sa[nq][mt], 0, 0, 0);
    }

    // p = mask ? exp2(s' - SHIFT2) : 0, truncate-pack to bf16 pairs in regs
    u32 pk[2][4][2];   // [nq][mt][lo/hi]
    #pragma unroll
    for (int nq = 0; nq < 2; ++nq) {
      u64 mq64 = mw[nq] >> (quad * 4);
      #pragma unroll
      for (int mt = 0; mt < 4; ++mt) {
        u32 nib = (u32)(mq64 >> (mt * 16)) & 0xFu;
        u32 pb[4];
        #pragma unroll
        for (int r = 0; r < 4; ++r) {
          float p = __builtin_amdgcn_exp2f(sa[nq][mt][r] - SM_SHIFT2);
          p = (nib >> r) & 1u ? p : 0.0f;
          pb[r] = __float_as_uint(p);
        }
        pk[nq][mt][0] = __builtin_amdgcn_perm(pb[1], pb[0], 0x07060302u);
        pk[nq][mt][1] = __builtin_amdgcn_perm(pb[3], pb[2], 0x07060302u);
      }
    }

    // O += P @ V ; l += P @ ones. P A-frags assembled via ds_bpermute.
    #pragma unroll
    for (int ks = 0; ks < 2; ++ks) {
      bf16x8 vb[4];
      #pragma unroll
      for (int dt = 0; dt < 4; ++dt)
        vb[dt] = ld_frag(lVc + dt * 1024 + ks * 512 + lane * 8);
      #pragma unroll
      for (int mq = 0; mq < 2; ++mq) {
        u32x4 regv;
        #pragma unroll
        for (int jr = 0; jr < 4; ++jr) {
          int idx = (jr < 2) ? idxA : idxB;
          int sel = jr & 1;
          u32 va = (u32)__builtin_amdgcn_ds_bpermute(idx, (int)pk[mq][2 * ks][sel]);
          u32 vbv = (u32)__builtin_amdgcn_ds_bpermute(idx, (int)pk[mq][2 * ks + 1][sel]);
          regv[jr] = hiTile ? vbv : va;
        }
        bf16x8 pa = __builtin_bit_cast(bf16x8, regv);
        #pragma unroll
        for (int dt = 0; dt < 4; ++dt)
          oa[mq][dt] = __builtin_amdgcn_mfma_f32_16x16x32_bf16(
              pa, vb[dt], oa[mq][dt], 0, 0, 0);
        oal[mq] = __builtin_amdgcn_mfma_f32_16x16x32_bf16(
            pa, ones, oal[mq], 0, 0, 0);
      }
    }

    mw[0] = mwn[0]; mw[1] = mwn[1];
    __syncthreads();
  }

  if (l15 == 0) {
    #pragma unroll
    for (int mq = 0; mq < 2; ++mq)
      #pragma unroll
      for (int r = 0; r < 4; ++r)
        lpart[((size_t)z * 16 + bh) * SEQ + q0 + wave * 32 + mq * 16 + quad * 4 + r] =
            oal[mq][r];
  }

  u16* Og = Opart + (size_t)z * NB_TOK * DD;
  #pragma unroll
  for (int mq = 0; mq < 2; ++mq)
    #pragma unroll
    for (int r = 0; r < 4; ++r) {
      int m = q0 + wave * 32 + mq * 16 + quad * 4 + r;
      u16* dst = Og + (size_t)(b * SEQ + m) * DD + h * 64;
      #pragma unroll
      for (int dt = 0; dt < 4; ++dt)
        dst[dt * 16 + l15] = f32_to_bf16(oa[mq][dt][r]);
    }
}

// ---------------------------------------------------------------------------
// merge 4 O/l partials + residual + rmsnorm2 + out-init (h + b3)
// ---------------------------------------------------------------------------
__global__ __launch_bounds__(256) void k_rms2(const float* __restrict__ x,
                                              const u16* __restrict__ Opart,
                                              const float* __restrict__ lpart,
                                              const float* __restrict__ b3,
                                              const float* __restrict__ g2,
                                              float* __restrict__ outinit,
                                              u16* __restrict__ hn) {
  int lane = threadIdx.x & 63, wave = threadIdx.x >> 6;
  int row = blockIdx.x * 4 + wave;
  int b = row >> 11, tok = row & 2047, hh = lane >> 3;
  size_t base = (size_t)row * DD + lane * 8;
  float lsum = 0.0f;
  #pragma unroll
  for (int z = 0; z < 4; ++z)
    lsum += lpart[((size_t)(z * 16 + b * 8 + hh)) * SEQ + tok];
  float inv = (lsum > 0.0f) ? (1.0f / lsum) : 0.0f;
  float ov[8] = {0,0,0,0,0,0,0,0};
  #pragma unroll
  for (int z = 0; z < 4; ++z) {
    us8 o = *(const us8*)(Opart + (size_t)z * NB_TOK * DD + base);
    #pragma unroll
    for (int j = 0; j < 8; ++j) ov[j] += bf16_to_f32(o[j]);
  }
  float4 a = *(const float4*)(x + base);
  float4 bb = *(const float4*)(x + base + 4);
  float hv[8];
  hv[0] = a.x  + ov[0] * inv; hv[1] = a.y  + ov[1] * inv;
  hv[2] = a.z  + ov[2] * inv; hv[3] = a.w  + ov[3] * inv;
  hv[4] = bb.x + ov[4] * inv; hv[5] = bb.y + ov[5] * inv;
  hv[6] = bb.z + ov[6] * inv; hv[7] = bb.w + ov[7] * inv;
  float ss = 0.0f;
  #pragma unroll
  for (int j = 0; j < 8; ++j) ss += hv[j] * hv[j];
  #pragma unroll
  for (int m = 1; m < 64; m <<= 1) ss += __shfl_xor(ss, m);
  float sc = rsqrtf(ss * (1.0f / DD) + EPS_F32);
  float4 c0 = *(const float4*)(b3 + lane * 8);
  float4 c1 = *(const float4*)(b3 + lane * 8 + 4);
  float4 w0 = {hv[0] + c0.x, hv[1] + c0.y, hv[2] + c0.z, hv[3] + c0.w};
  float4 w1 = {hv[4] + c1.x, hv[5] + c1.y, hv[6] + c1.z, hv[7] + c1.w};
  *(float4*)(outinit + base) = w0;
  *(float4*)(outinit + base + 4) = w1;
  float4 ga = *(const float4*)(g2 + lane * 8);
  float4 gb = *(const float4*)(g2 + lane * 8 + 4);
  us8 hb;
  hb[0] = f32_to_bf16(hv[0] * sc * ga.x); hb[1] = f32_to_bf16(hv[1] * sc * ga.y);
  hb[2] = f32_to_bf16(hv[2] * sc * ga.z); hb[3] = f32_to_bf16(hv[3] * sc * ga.w);
  hb[4] = f32_to_bf16(hv[4] * sc * gb.x); hb[5] = f32_to_bf16(hv[5] * sc * gb.y);
  hb[6] = f32_to_bf16(hv[6] * sc * gb.z); hb[7] = f32_to_bf16(hv[7] * sc * gb.w);
  *(us8*)(hn + base) = hb;
}

// ---------------------------------------------------------------------------
// FFN1+FFN2 fused; grid (32 mblk fast, 32 nblk of 64)
// ---------------------------------------------------------------------------
__global__ __launch_bounds__(256, 4) void k_ffn12(const u16* __restrict__ hn,
                                                  const u16* __restrict__ w1,
                                                  const u16* __restrict__ w2,
                                                  const float* __restrict__ b1,
                                                  const float* __restrict__ b2,
                                                  u16* __restrict__ g) {
  __shared__ u16 lA[8192], lB[8192];
  int mblk = blockIdx.x * 128, nblk = blockIdx.y * 64;
  f32x4 acc[2][4][2];
  #pragma unroll
  for (int bi = 0; bi < 2; ++bi)
    #pragma unroll
    for (int mt = 0; mt < 4; ++mt)
      #pragma unroll
      for (int nt = 0; nt < 2; ++nt) acc[bi][mt][nt] = (f32x4)0.0f;
  gemm32<2>(hn, w1, w2, DD, mblk, nblk, 0, 16, lA, lB, acc);
  int lane = threadIdx.x & 63, wave = threadIdx.x >> 6;
  int l15 = lane & 15, quad = lane >> 4;
  int wm = (wave >> 1) * 64, wn = (wave & 1) * 32;
  #pragma unroll
  for (int mt = 0; mt < 4; ++mt)
    #pragma unroll
    for (int nt = 0; nt < 2; ++nt) {
      int n = nblk + wn + nt * 16 + l15;
      float bb1 = b1[n], bb2 = b2[n];
      #pragma unroll
      for (int r = 0; r < 4; ++r) {
        int m = mblk + wm + mt * 16 + quad * 4 + r;
        float x2 = acc[0][mt][nt][r] + bb1;
        float x3 = acc[1][mt][nt][r] + bb2;
        float si = x2 / (1.0f + __expf(-x2));
        g[(size_t)m * HDIM + n] = f32_to_bf16(si * x3);
      }
    }
}

// ---------------------------------------------------------------------------
// FFN3 split-K=2, NO atomics: partial[z] = g[:, z*1024:(z+1)*1024] @ W3^T
// slice. grid (32 mblk fast, 8 nblk of 64, 2 z). f32 partials to workspace.
// ---------------------------------------------------------------------------
__global__ __launch_bounds__(256, 4) void k_ffn3(const u16* __restrict__ g,
                                                 const u16* __restrict__ w3,
                                                 float* __restrict__ p0,
                                                 float* __restrict__ p1) {
  __shared__ u16 lA[8192], lB[4096];
  int mblk = blockIdx.x * 128, nblk = blockIdx.y * 64, z = blockIdx.z;
  f32x4 acc[1][4][2];
  #pragma unroll
  for (int mt = 0; mt < 4; ++mt)
    #pragma unroll
    for (int nt = 0; nt < 2; ++nt) acc[0][mt][nt] = (f32x4)0.0f;
  gemm32<1>(g, w3, nullptr, HDIM, mblk, nblk, z * 1024, 32, lA, lB, acc);
  float* dst = z ? p1 : p0;
  int lane = threadIdx.x & 63, wave = threadIdx.x >> 6;
  int l15 = lane & 15, quad = lane >> 4;
  int wm = (wave >> 1) * 64, wn = (wave & 1) * 32;
  #pragma unroll
  for (int mt = 0; mt < 4; ++mt)
    #pragma unroll
    for (int nt = 0; nt < 2; ++nt) {
      int n = nblk + wn + nt * 16 + l15;
      #pragma unroll
      for (int r = 0; r < 4; ++r) {
        int m = mblk + wm + mt * 16 + quad * 4 + r;
        dst[(size_t)m * DD + n] = acc[0][mt][nt][r];
      }
    }
}

// ---------------------------------------------------------------------------
// merge: out(pre-inited h+b3) += p0 + p1.  2M f32 elems, float4 streaming.
// ---------------------------------------------------------------------------
__global__ __launch_bounds__(256) void k_fmerge(const float* __restrict__ p0,
                                                const float* __restrict__ p1,
                                                float* __restrict__ out) {
  int e = (blockIdx.x * 256 + threadIdx.x) * 4;
  float4 a = *(const float4*)(p0 + e);
  float4 b = *(const float4*)(p1 + e);
  float4 o = *(const float4*)(out + e);
  o.x += a.x + b.x; o.y += a.y + b.y;
  o.z += a.z + b.z; o.w += a.w + b.w;
  *(float4*)(out + e) = o;
}

// ---------------------------------------------------------------------------
// workspace layout (bytes).  p0/p1 reuse regions dead after qkv/attn/ffn12:
// p0 = MB16 (qb+kb region, 8 MB), p1 = MB0 (xn+wqkv+w1b region, 8 MB).
// ---------------------------------------------------------------------------
#define MB(x) ((size_t)(x) * 1048576)
#define WS_XN    MB(0)     // 4 MiB  bf16 [4096][512]   (dead after k_qkv)
#define WS_WQKV  MB(4)     // 1.5                       (dead after k_qkv)
#define WS_W1B   MB(6)     // 2                         (dead after k_ffn12)
#define WS_W2B   MB(8)     // 2
#define WS_W3B   MB(10)    // 2
#define WS_MASK  MB(12)    // 1   u64 [2][32][2048]
#define WS_QB    MB(16)    // 4                          (dead after k_attn)
#define WS_KB    MB(20)    // 4                          (dead after k_attn)
#define WS_VT    MB(24)    // 4   bf16 [16*64][2048]     (dead after k_attn)
#define WS_OP    MB(28)    // 16  bf16 [4][4096][512]
#define WS_LP    MB(44)    // 0.5 f32 [4][16][2048]
#define WS_HN    MB(45)    // 4
#define WS_G     MB(49)    // 16
#define WS_P0    MB(16)    // 8   f32 [4096][512] ffn3 partial z=0
#define WS_P1    MB(0)     // 8   f32 [4096][512] ffn3 partial z=1

extern "C" void kernel_launch(void* const* d_in, const int* in_sizes, int n_in,
                              void* d_out, int out_size, void* d_ws, size_t ws_size,
                              hipStream_t stream) {
  (void)in_sizes; (void)n_in; (void)out_size; (void)ws_size;
  const float* x  = (const float*)d_in[0];
  const int*   DA = (const int*)d_in[1];
  const float* Wq = (const float*)d_in[2];
  const float* bq = (const float*)d_in[3];
  const float* Wk = (const float*)d_in[4];
  const float* bk = (const float*)d_in[5];
  const float* Wv = (const float*)d_in[6];
  const float* bv = (const float*)d_in[7];
  const float* W1 = (const float*)d_in[8];
  const float* b1 = (const float*)d_in[9];
  const float* W2 = (const float*)d_in[10];
  const float* b2 = (const float*)d_in[11];
  const float* W3 = (const float*)d_in[12];
  const float* b3 = (const float*)d_in[13];
  const float* g1 = (const float*)d_in[14];
  const float* g2 = (const float*)d_in[15];
  float* out = (float*)d_out;
  char* w = (char*)d_ws;

  u16* xn   = (u16*)(w + WS_XN);
  u16* wqkv = (u16*)(w + WS_WQKV);
  u16* w1b  = (u16*)(w + WS_W1B);
  u16* w2b  = (u16*)(w + WS_W2B);
  u16* w3b  = (u16*)(w + WS_W3B);
  u64* mskT = (u64*)(w + WS_MASK);
  u16* qb   = (u16*)(w + WS_QB);
  u16* kb   = (u16*)(w + WS_KB);
  u16* vt   = (u16*)(w + WS_VT);
  u16* Op   = (u16*)(w + WS_OP);
  float* lp = (float*)(w + WS_LP);
  u16* hn   = (u16*)(w + WS_HN);
  u16* gb   = (u16*)(w + WS_G);
  float* p0 = (float*)(w + WS_P0);
  float* p1 = (float*)(w + WS_P1);

  k_pre<<<5888, 256, 0, stream>>>(Wq, Wk, Wv, W1, W2, W3, DA, x, g1,
                                  wqkv, w1b, w2b, w3b, mskT, xn);
  k_qkv<<<dim3(32, 8, 3), 256, 0, stream>>>(xn, wqkv, bq, bk, bv, qb, kb, vt);
  k_attn<<<dim3(16, 16, 4), 256, 0, stream>>>(qb, kb, vt, mskT, Op, lp);
  k_rms2<<<1024, 256, 0, stream>>>(x, Op, lp, b3, g2, out, hn);
  k_ffn12<<<dim3(32, 32), 256, 0, stream>>>(hn, w1b, w2b, b1, b2, gb);
  k_ffn3<<<dim3(32, 8, 2), 256, 0, stream>>>(gb, w3b, p0, p1);
  k_fmerge<<<2048, 256, 0, stream>>>(p0, p1, out);
}